// Round 10
// baseline (306.176 us; speedup 1.0000x reference)
//
#include <hip/hip_runtime.h>
#include <math.h>

#define BLK 256

constexpr int Bg    = 2048;
constexpr int Fn    = 64;
constexpr int DIN   = 32;
constexpr int Hd    = 128;
constexpr int HEADS = 4;
constexpr int NC    = 16;
constexpr int EPG   = 128;
constexpr int Etot  = Bg * EPG;
constexpr int W1C   = HEADS * Hd;   // 512
constexpr int NSTR  = 68;           // hT row stride (bf16): stride 34 words -> 2-way max
constexpr int EROW  = 136;          // eluS row stride (bf16)
constexpr int PROW  = 68;           // Pbf row stride (bf16)
constexpr int NE    = EPG + Fn;     // 192 edges incl self-loops

typedef __attribute__((ext_vector_type(8))) __bf16 bf16x8;
typedef __attribute__((ext_vector_type(4))) __bf16 bf16x4;
typedef __attribute__((ext_vector_type(4))) float  f32x4;

// ---- precomputed weights (single prep kernel) ----
__device__ __align__(16) __bf16 g_wcombT[W1C * DIN];
__device__ float g_c1[W1C];
__device__ float g_c1s[16];
__device__ __align__(16) __bf16 g_w2F[HEADS*4*8*64*8];      // 65536 elems
__device__ __align__(16) __bf16 g_wscF[HEADS*4*64*8];       // 8192 elems
__device__ __align__(16) __bf16 g_bs1F[64*8];               // 512 elems

constexpr int N_WC   = DIN * W1C;
constexpr int C0 = N_WC;
constexpr int C1 = C0 + W1C;
constexpr int C2 = C1 + HEADS*4*8*64*8;
constexpr int C3 = C2 + HEADS*4*64*8;
constexpr int C4 = C3 + 4096;
constexpr int C5 = C4 + 512;
constexpr int C6 = C5 + 8192;
constexpr int CP_TOT = C6 + 256;

__global__ __launch_bounds__(BLK) void prep(
    const float* __restrict__ Wa, const float* __restrict__ ba,
    const float* __restrict__ W1, const float* __restrict__ W2,
    const float* __restrict__ as1, const float* __restrict__ ad1,
    const float* __restrict__ as2, const float* __restrict__ ad2)
{
  __shared__ float WaS[DIN * Hd];
  const int tid = threadIdx.x;
  if (blockIdx.x < 64) {
    for (int i2 = tid; i2 < DIN * Hd; i2 += BLK) {
      int k = i2 >> 7, m = i2 & 127;
      WaS[m * DIN + k] = Wa[i2];
    }
    __syncthreads();
  }

  int i = blockIdx.x * BLK + tid;
  if (i < C0) {                                         // wcombT: i = n*32+k
    int k = i & 31, n = i >> 5;
    float a0=0.f,a1=0.f,a2=0.f,a3=0.f;
    #pragma unroll
    for (int m = 0; m < Hd; m += 4) {
      a0 += WaS[(m  )*DIN + k] * W1[(m  )*W1C + n];
      a1 += WaS[(m+1)*DIN + k] * W1[(m+1)*W1C + n];
      a2 += WaS[(m+2)*DIN + k] * W1[(m+2)*W1C + n];
      a3 += WaS[(m+3)*DIN + k] * W1[(m+3)*W1C + n];
    }
    g_wcombT[i] = (__bf16)(a0+a1+a2+a3);
  } else if (i < C1) {                                  // c1
    int n = i - C0;
    float a0=0.f,a1=0.f,a2=0.f,a3=0.f;
    #pragma unroll
    for (int m = 0; m < Hd; m += 4) {
      a0 += ba[m  ] * W1[(m  )*W1C + n];
      a1 += ba[m+1] * W1[(m+1)*W1C + n];
      a2 += ba[m+2] * W1[(m+2)*W1C + n];
      a3 += ba[m+3] * W1[(m+3)*W1C + n];
    }
    g_c1[n] = a0+a1+a2+a3;
  } else if (i < C2) {                                  // w2F
    int j = i - C1;
    int k = j >> 7, n = j & 127;
    int hh = k >> 7, Ks = (k >> 5) & 3, q = (k >> 3) & 3, jj = k & 7;
    int Nt = n >> 4, l = n & 15;
    int idx = (((hh*4 + Ks)*8 + Nt)*64 + (q*16 + l))*8 + jj;
    g_w2F[idx] = (__bf16)W2[j];
  } else if (i < C3) {                                  // wscF zero (c >= 2)
    int j = i - C2;
    int lane = (j >> 3) & 63, c = lane & 15;
    if (c >= 2) g_wscF[j] = (__bf16)0.f;
  } else if (i < C4) {                                  // wscF dots
    int j = i - C3;
    int p = j & 3, c = (j >> 2) & 1, k = j >> 3;
    const float* av = c ? ad2 : as2;
    float a0=0.f,a1=0.f,a2=0.f,a3=0.f;
    #pragma unroll
    for (int q = 0; q < 32; q += 4) {
      int f = p*32 + q;
      a0 += W2[(size_t)k*Hd + f    ] * av[f    ];
      a1 += W2[(size_t)k*Hd + f + 1] * av[f + 1];
      a2 += W2[(size_t)k*Hd + f + 2] * av[f + 2];
      a3 += W2[(size_t)k*Hd + f + 3] * av[f + 3];
    }
    float a = a0+a1+a2+a3;
    a += __shfl_xor(a, 1);
    a += __shfl_xor(a, 2);
    if (p == 0) {
      int T = k >> 5, q2 = (k >> 3) & 3, jj = k & 7;
      g_wscF[(T*64 + q2*16 + c)*8 + jj] = (__bf16)a;
    }
  } else if (i < C5) {                                  // bs1F zero (c >= 8)
    int j = i - C4;
    int lane = j >> 3, c = lane & 15;
    if (c >= 8) g_bs1F[j] = (__bf16)0.f;
  } else if (i < C6) {                                  // bs1F dots
    int j = i - C5;
    int p = j & 31, c = (j >> 5) & 7, kk = j >> 8;
    int h = c >> 1;
    const float* av = (c & 1) ? (ad1 + h*Hd) : (as1 + h*Hd);
    float acc = 0.f;
    #pragma unroll
    for (int mi = 0; mi < 4; ++mi) {
      int m = p*4 + mi;
      float t0=0.f,t1=0.f,t2=0.f,t3=0.f;
      #pragma unroll
      for (int f = 0; f < Hd; f += 4) {
        t0 += W1[m*W1C + h*Hd + f    ] * av[f    ];
        t1 += W1[m*W1C + h*Hd + f + 1] * av[f + 1];
        t2 += W1[m*W1C + h*Hd + f + 2] * av[f + 2];
        t3 += W1[m*W1C + h*Hd + f + 3] * av[f + 3];
      }
      acc += Wa[kk*Hd + m] * (t0+t1+t2+t3);
    }
    acc += __shfl_xor(acc, 1);
    acc += __shfl_xor(acc, 2);
    acc += __shfl_xor(acc, 4);
    acc += __shfl_xor(acc, 8);
    acc += __shfl_xor(acc, 16);
    if (p == 0) {
      int q2 = kk >> 3, jj = kk & 7;
      g_bs1F[(q2*16 + c)*8 + jj] = (__bf16)acc;
    }
  } else if (i < CP_TOT) {                              // c1s
    int j = i - C6;
    int p = j & 31, c = j >> 5;
    int h = c >> 1;
    const float* av = (c & 1) ? (ad1 + h*Hd) : (as1 + h*Hd);
    float acc = 0.f;
    #pragma unroll
    for (int mi = 0; mi < 4; ++mi) {
      int m = p*4 + mi;
      float t = 0.f;
      #pragma unroll
      for (int f = 0; f < Hd; ++f) t += W1[m*W1C + h*Hd + f] * av[f];
      acc += ba[m] * t;
    }
    acc += __shfl_xor(acc, 1);
    acc += __shfl_xor(acc, 2);
    acc += __shfl_xor(acc, 4);
    acc += __shfl_xor(acc, 8);
    acc += __shfl_xor(acc, 16);
    if (p == 0) g_c1s[c] = acc;
  }
}

// ================= main fused kernel =================
// R10: hT and eluS ALIAS one 17.4 KB buffer (they are never simultaneously
// live: hT[h] dies when phase-Cm's aggregation MFMAs have read it; eluS is
// written strictly after, behind a barrier). LDS 47.6 -> ~30 KB => 5 blocks/CU.
__global__ __launch_bounds__(BLK, 5) void gat_main(
    const float* __restrict__ emb, const int* __restrict__ ei,
    const float* __restrict__ gate_logits,
    const float* __restrict__ b1, const float* __restrict__ b2,
    const float* __restrict__ Wc1, const float* __restrict__ bc1,
    const float* __restrict__ Wc2, const float* __restrict__ bc2,
    float* __restrict__ out)
{
  __shared__ __align__(16) __bf16 hbuf[Hd * NSTR];  // 17408 B: hT / eluS / cells alias
  __shared__ __align__(16) __bf16 Pbf[Fn * PROW];   //  8704 B: bf16 P [tgt][src]
  __shared__ float sS1s[HEADS][Fn], sS1d[HEADS][Fn];// 2048 B
  __shared__ float sSrc[Fn], sDst[Fn], sSum[Fn], gateS[Fn];
  __shared__ float gpool[Hd], hcS[Fn];
  __shared__ __align__(16) __bf16 wS[Fn];

  __bf16* hT   = hbuf;                              // [feat(128)][node], stride NSTR
  __bf16* eluS = hbuf;                              // [node(64)][feat], stride EROW
  unsigned* cells = (unsigned*)hbuf;                // 4096 u32 (setup only)

  const int b    = blockIdx.x;
  const int tid  = threadIdx.x;
  const int lane = tid & 63;
  const int wv   = tid >> 6;
  const int quad = lane >> 4;
  const int l15  = lane & 15;
  const int nodeBase = wv * 16;
  const int m0   = wv * 32;
  const int base = b * Fn;

  const f32x4 zero4 = {0.f, 0.f, 0.f, 0.f};

  // ---- S1a: zero cells/Pbf/sSum, gate, stage edges to regs ----
  int es = 0, et = 0, ecell = 0;
  if (tid < NE) {
    if (tid < EPG) {
      es = ei[(size_t)b*EPG + tid] - base;
      et = ei[(size_t)Etot + (size_t)b*EPG + tid] - base;
    } else {
      es = et = tid - EPG;
    }
    ecell = et * Fn + es;
  }
  #pragma unroll
  for (int i = 0; i < 16; ++i) cells[tid + i*BLK] = 0u;
  {
    float4* p4 = (float4*)Pbf;                      // 544 float4
    const float4 z4 = {0.f,0.f,0.f,0.f};
    p4[tid] = z4; p4[tid + 256] = z4;
    if (tid < 32) p4[tid + 512] = z4;
  }
  if (tid < Fn) {
    float g = 1.f / (1.f + expf(-gate_logits[tid]));
    gateS[tid] = g; sSum[tid] = 0.f;
    if (b == 0) out[Bg*NC + tid] = g;               // second tuple output (gate)
  }
  // A-fragment of emb (constant across heads)
  bf16x8 Af;
  {
    const float* ar = emb + ((size_t)base + nodeBase + l15) * DIN + quad * 8;
    float4 e0 = *(const float4*)ar;
    float4 e1 = *(const float4*)(ar + 4);
    Af[0]=(__bf16)e0.x; Af[1]=(__bf16)e0.y; Af[2]=(__bf16)e0.z; Af[3]=(__bf16)e0.w;
    Af[4]=(__bf16)e1.x; Af[5]=(__bf16)e1.y; Af[6]=(__bf16)e1.z; Af[7]=(__bf16)e1.w;
  }
  __syncthreads();

  // ---- S1b: edge multiplicity count + layer-1 score MFMA ----
  bool rep = false;
  if (tid < NE) rep = (atomicAdd(&cells[ecell], 1u) == 0u);
  {
    bf16x8 Bs = *(const bf16x8*)(g_bs1F + lane*8);
    f32x4 ds = __builtin_amdgcn_mfma_f32_16x16x32_bf16(Af, Bs, zero4, 0, 0, 0);
    if (l15 < 8) {
      const float cc = g_c1s[l15];
      const int h = l15 >> 1;
      float* dstArr = (l15 & 1) ? &sS1d[h][0] : &sS1s[h][0];
      #pragma unroll
      for (int r = 0; r < 4; ++r) {
        int m = nodeBase + quad*4 + r;
        dstArr[m] = gateS[m] * (ds[r] + cc);
      }
    }
  }
  __syncthreads();

  float fm = 0.f;
  if (tid < NE && rep) fm = (float)cells[ecell];
  __syncthreads();                                  // cells region becomes hT next

  float gq[4];
  #pragma unroll
  for (int r = 0; r < 4; ++r) gq[r] = gateS[nodeBase + quad*4 + r];

  f32x4 acc[8];                                     // GEMM2 accumulators
  #pragma unroll
  for (int i = 0; i < 8; ++i) acc[i] = zero4;
  f32x4 accS = zero4;                               // layer-2 score accumulator

  for (int hh = 0; hh < HEADS; ++hh) {
    // ---- P1: GEMM1 -> hT  ||  edge scatter into Pbf/sSum ----
    #pragma unroll
    for (int Nt = 0; Nt < 8; ++Nt) {
      const int n = Nt*16 + l15;
      bf16x8 Bf = *(const bf16x8*)(g_wcombT + (hh*Hd + n)*DIN + quad*8);  // coalesced
      f32x4 d = __builtin_amdgcn_mfma_f32_16x16x32_bf16(Af, Bf, zero4, 0, 0, 0);
      const float c1v = g_c1[hh*Hd + n];
      bf16x4 hw;
      #pragma unroll
      for (int r = 0; r < 4; ++r) hw[r] = (__bf16)((d[r] + c1v) * gq[r]);
      *(bf16x4*)(hT + n*NSTR + nodeBase + quad*4) = hw;
    }
    if (tid < NE && rep) {
      float e = sS1s[hh][es] + sS1d[hh][et];
      e = (e > 0.f) ? e : 0.2f * e;
      float pe = fm * __expf(e);
      Pbf[et*PROW + es] = (__bf16)pe;
      atomicAdd(&sSum[et], pe);
    }
    __syncthreads();

    // ---- P2 (Cm): aggregation MFMAs + epilogue -> 8 bf16x4 regs (hT dies here) ----
    bf16x4 w[4][2];
    {
      bf16x8 Ac[2][2];
      #pragma unroll
      for (int Mi = 0; Mi < 2; ++Mi)
        #pragma unroll
        for (int Ks = 0; Ks < 2; ++Ks)
          Ac[Mi][Ks] = *(const bf16x8*)(hT + (m0 + Mi*16 + l15)*NSTR + Ks*32 + quad*8);
      float4 b1v[2];
      #pragma unroll
      for (int Mi = 0; Mi < 2; ++Mi)
        b1v[Mi] = *(const float4*)&b1[hh*Hd + m0 + Mi*16 + quad*4];
      #pragma unroll
      for (int Nt = 0; Nt < 4; ++Nt) {
        bf16x8 B0f = *(const bf16x8*)(Pbf + (Nt*16 + l15)*PROW + quad*8);
        bf16x8 B1f = *(const bf16x8*)(Pbf + (Nt*16 + l15)*PROW + 32 + quad*8);
        const int t = Nt*16 + l15;
        const float si = 1.f / (sSum[t] + 1e-16f);
        #pragma unroll
        for (int Mi = 0; Mi < 2; ++Mi) {
          f32x4 d = __builtin_amdgcn_mfma_f32_16x16x32_bf16(Ac[Mi][0], B0f, zero4, 0, 0, 0);
          d = __builtin_amdgcn_mfma_f32_16x16x32_bf16(Ac[Mi][1], B1f, d, 0, 0, 0);
          #pragma unroll
          for (int r = 0; r < 4; ++r) {
            float hv = d[r]*si + b1v[Mi][r];
            hv = (hv > 0.f) ? hv : (__expf(hv) - 1.f);
            w[Nt][Mi][r] = (__bf16)hv;
          }
        }
      }
    }
    __syncthreads();                                // all hT reads + Pbf reads done

    // ---- P3 (Ce): write elu -> eluS (same memory as hT); zero Pbf ----
    #pragma unroll
    for (int Nt = 0; Nt < 4; ++Nt) {
      const int t = Nt*16 + l15;
      #pragma unroll
      for (int Mi = 0; Mi < 2; ++Mi)
        *(bf16x4*)(eluS + t*EROW + m0 + Mi*16 + quad*4) = w[Nt][Mi];
    }
    {
      float4* p4 = (float4*)Pbf;
      const float4 z4 = {0.f,0.f,0.f,0.f};
      p4[tid] = z4; p4[tid + 256] = z4;
      if (tid < 32) p4[tid + 512] = z4;
    }
    __syncthreads();

    // ---- P4 (D): GEMM2 + fused layer-2 score column; zero sSum ----
    #pragma unroll
    for (int Ks = 0; Ks < 4; ++Ks) {
      bf16x8 A2 = *(const bf16x8*)(eluS + (nodeBase + l15)*EROW + Ks*32 + quad*8);
      #pragma unroll
      for (int Nt = 0; Nt < 8; ++Nt) {
        bf16x8 B2 = *(const bf16x8*)(g_w2F + (((hh*4 + Ks)*8 + Nt)*64 + lane)*8);
        acc[Nt] = __builtin_amdgcn_mfma_f32_16x16x32_bf16(A2, B2, acc[Nt], 0, 0, 0);
      }
      bf16x8 Bs2 = *(const bf16x8*)(g_wscF + ((hh*4 + Ks)*64 + lane)*8);
      accS = __builtin_amdgcn_mfma_f32_16x16x32_bf16(A2, Bs2, accS, 0, 0, 0);
    }
    if (tid < Fn) sSum[tid] = 0.f;
    __syncthreads();                                // eluS dies; next P1 rewrites hbuf
  }

  // ---- E: publish h2 -> hT; extract layer-2 scores from accS ----
  #pragma unroll
  for (int Nt = 0; Nt < 8; ++Nt) {
    const int n = Nt*16 + l15;
    bf16x4 hw;
    #pragma unroll
    for (int r = 0; r < 4; ++r) hw[r] = (__bf16)acc[Nt][r];
    *(bf16x4*)(hT + n*NSTR + nodeBase + quad*4) = hw;
  }
  if (l15 == 0) {
    #pragma unroll
    for (int r = 0; r < 4; ++r) sSrc[nodeBase + quad*4 + r] = accS[r];
  } else if (l15 == 1) {
    #pragma unroll
    for (int r = 0; r < 4; ++r) sDst[nodeBase + quad*4 + r] = accS[r];
  }
  __syncthreads();

  // ---- F: layer-2 edge scatter ----
  if (tid < NE && rep) {
    float e = sSrc[es] + sDst[et];
    e = (e > 0.f) ? e : 0.2f * e;
    float pe = fm * __expf(e);
    Pbf[et*PROW + es] = (__bf16)pe;
    atomicAdd(&sSum[et], pe);
  }
  __syncthreads();

  // ---- W: w[s] = (1/64) * sum_t sInv_t * P2[t][s] ----
  {
    const int s_ = tid >> 2, part = tid & 3;
    float a = 0.f;
    #pragma unroll
    for (int q = 0; q < 16; ++q) {
      const int t = part*16 + q;
      a += (1.f / (sSum[t] + 1e-16f)) * (float)Pbf[t*PROW + s_];
    }
    a += __shfl_xor(a, 1);
    a += __shfl_xor(a, 2);
    if (part == 0) wS[s_] = (__bf16)(a * (1.f/64.f));
  }
  __syncthreads();

  // ---- G: gpool[f] = h2^T[f] · w + b2[f] ----
  {
    #pragma unroll
    for (int Mi = 0; Mi < 2; ++Mi) {
      f32x4 d = zero4;
      #pragma unroll
      for (int Ks = 0; Ks < 2; ++Ks) {
        bf16x8 A = *(const bf16x8*)(hT + (m0 + Mi*16 + l15)*NSTR + Ks*32 + quad*8);
        bf16x8 Bw = *(const bf16x8*)(wS + Ks*32 + quad*8);   // broadcast
        d = __builtin_amdgcn_mfma_f32_16x16x32_bf16(A, Bw, d, 0, 0, 0);
      }
      if (l15 == 0) {
        #pragma unroll
        for (int r = 0; r < 4; ++r) {
          const int f = m0 + Mi*16 + quad*4 + r;
          gpool[f] = d[r] + b2[f];
        }
      }
    }
  }
  __syncthreads();

  // ---- classifier layer 1: hc = leaky(g @ Wc1 + bc1), 4 threads/col ----
  {
    const int c = tid >> 2, p = tid & 3;
    float a = 0.f;
    #pragma unroll
    for (int i = 0; i < 32; ++i) {
      const int k = p*32 + i;
      a += gpool[k] * Wc1[k*Fn + c];
    }
    a += __shfl_xor(a, 1);
    a += __shfl_xor(a, 2);
    if (p == 0) {
      a += bc1[c];
      hcS[c] = (a > 0.f) ? a : 0.01f * a;
    }
  }
  __syncthreads();

  // ---- classifier layer 2: logits, 16 threads/col ----
  {
    const int c = tid >> 4, p = tid & 15;
    float a = 0.f;
    #pragma unroll
    for (int i = 0; i < 4; ++i) {
      const int k = p*4 + i;
      a += hcS[k] * Wc2[k*NC + c];
    }
    a += __shfl_xor(a, 1);
    a += __shfl_xor(a, 2);
    a += __shfl_xor(a, 4);
    a += __shfl_xor(a, 8);
    if (p == 0) out[b*NC + c] = a + bc2[c];
  }
}

extern "C" void kernel_launch(void* const* d_in, const int* in_sizes, int n_in,
                              void* d_out, int out_size, void* d_ws, size_t ws_size,
                              hipStream_t stream) {
  const float* emb = (const float*)d_in[0];
  const int*   ei  = (const int*)  d_in[1];
  // d_in[2] = batch_idx (layout known)
  const float* Wa  = (const float*)d_in[3];
  const float* ba  = (const float*)d_in[4];
  const float* gl  = (const float*)d_in[5];
  const float* W1  = (const float*)d_in[6];
  const float* as1 = (const float*)d_in[7];
  const float* ad1 = (const float*)d_in[8];
  const float* b1  = (const float*)d_in[9];
  const float* W2  = (const float*)d_in[10];
  const float* as2 = (const float*)d_in[11];
  const float* ad2 = (const float*)d_in[12];
  const float* b2  = (const float*)d_in[13];
  const float* Wc1 = (const float*)d_in[14];
  const float* bc1 = (const float*)d_in[15];
  const float* Wc2 = (const float*)d_in[16];
  const float* bc2 = (const float*)d_in[17];
  float* out = (float*)d_out;

  hipLaunchKernelGGL(prep, dim3((CP_TOT + BLK - 1)/BLK), dim3(BLK), 0, stream,
                     Wa, ba, W1, W2, as1, ad1, as2, ad2);
  hipLaunchKernelGGL(gat_main, dim3(Bg), dim3(BLK), 0, stream,
                     emb, ei, gl, b1, b2, Wc1, bc1, Wc2, bc2, out);
}

// Round 11
// 215.858 us; speedup vs baseline: 1.4184x; 1.4184x over previous
//
#include <hip/hip_runtime.h>
#include <math.h>

#define BLK 256

constexpr int Bg    = 2048;
constexpr int Fn    = 64;
constexpr int DIN   = 32;
constexpr int Hd    = 128;
constexpr int HEADS = 4;
constexpr int NC    = 16;
constexpr int EPG   = 128;
constexpr int Etot  = Bg * EPG;
constexpr int W1C   = HEADS * Hd;   // 512
constexpr int NSTR  = 68;           // hT row stride (bf16)
constexpr int EROW  = 136;          // eluS row stride (bf16)
constexpr int PROW  = 68;           // Pbf row stride (bf16)
constexpr int NE    = EPG + Fn;     // 192 edges incl self-loops

typedef __attribute__((ext_vector_type(8))) __bf16 bf16x8;
typedef __attribute__((ext_vector_type(4))) __bf16 bf16x4;
typedef __attribute__((ext_vector_type(4))) float  f32x4;

// ---- precomputed weights (single prep kernel) ----
__device__ __align__(16) __bf16 g_wcombT[W1C * DIN];
__device__ float g_c1[W1C];
__device__ float g_c1s[16];
__device__ __align__(16) __bf16 g_w2F[HEADS*4*8*64*8];      // 65536 elems
__device__ __align__(16) __bf16 g_wscF[HEADS*4*64*8];       // 8192 elems
__device__ __align__(16) __bf16 g_bs1F[64*8];               // 512 elems

constexpr int N_WC   = DIN * W1C;
constexpr int C0 = N_WC;
constexpr int C1 = C0 + W1C;
constexpr int C2 = C1 + HEADS*4*8*64*8;
constexpr int C3 = C2 + HEADS*4*64*8;
constexpr int C4 = C3 + 4096;
constexpr int C5 = C4 + 512;
constexpr int C6 = C5 + 8192;
constexpr int CP_TOT = C6 + 256;

__global__ __launch_bounds__(BLK) void prep(
    const float* __restrict__ Wa, const float* __restrict__ ba,
    const float* __restrict__ W1, const float* __restrict__ W2,
    const float* __restrict__ as1, const float* __restrict__ ad1,
    const float* __restrict__ as2, const float* __restrict__ ad2)
{
  __shared__ float WaS[DIN * Hd];
  const int tid = threadIdx.x;
  if (blockIdx.x < 64) {
    for (int i2 = tid; i2 < DIN * Hd; i2 += BLK) {
      int k = i2 >> 7, m = i2 & 127;
      WaS[m * DIN + k] = Wa[i2];
    }
    __syncthreads();
  }

  int i = blockIdx.x * BLK + tid;
  if (i < C0) {                                         // wcombT: i = n*32+k
    int k = i & 31, n = i >> 5;
    float a0=0.f,a1=0.f,a2=0.f,a3=0.f;
    #pragma unroll
    for (int m = 0; m < Hd; m += 4) {
      a0 += WaS[(m  )*DIN + k] * W1[(m  )*W1C + n];
      a1 += WaS[(m+1)*DIN + k] * W1[(m+1)*W1C + n];
      a2 += WaS[(m+2)*DIN + k] * W1[(m+2)*W1C + n];
      a3 += WaS[(m+3)*DIN + k] * W1[(m+3)*W1C + n];
    }
    g_wcombT[i] = (__bf16)(a0+a1+a2+a3);
  } else if (i < C1) {                                  // c1
    int n = i - C0;
    float a0=0.f,a1=0.f,a2=0.f,a3=0.f;
    #pragma unroll
    for (int m = 0; m < Hd; m += 4) {
      a0 += ba[m  ] * W1[(m  )*W1C + n];
      a1 += ba[m+1] * W1[(m+1)*W1C + n];
      a2 += ba[m+2] * W1[(m+2)*W1C + n];
      a3 += ba[m+3] * W1[(m+3)*W1C + n];
    }
    g_c1[n] = a0+a1+a2+a3;
  } else if (i < C2) {                                  // w2F
    int j = i - C1;
    int k = j >> 7, n = j & 127;
    int hh = k >> 7, Ks = (k >> 5) & 3, q = (k >> 3) & 3, jj = k & 7;
    int Nt = n >> 4, l = n & 15;
    int idx = (((hh*4 + Ks)*8 + Nt)*64 + (q*16 + l))*8 + jj;
    g_w2F[idx] = (__bf16)W2[j];
  } else if (i < C3) {                                  // wscF zero (c >= 2)
    int j = i - C2;
    int lane = (j >> 3) & 63, c = lane & 15;
    if (c >= 2) g_wscF[j] = (__bf16)0.f;
  } else if (i < C4) {                                  // wscF dots
    int j = i - C3;
    int p = j & 3, c = (j >> 2) & 1, k = j >> 3;
    const float* av = c ? ad2 : as2;
    float a0=0.f,a1=0.f,a2=0.f,a3=0.f;
    #pragma unroll
    for (int q = 0; q < 32; q += 4) {
      int f = p*32 + q;
      a0 += W2[(size_t)k*Hd + f    ] * av[f    ];
      a1 += W2[(size_t)k*Hd + f + 1] * av[f + 1];
      a2 += W2[(size_t)k*Hd + f + 2] * av[f + 2];
      a3 += W2[(size_t)k*Hd + f + 3] * av[f + 3];
    }
    float a = a0+a1+a2+a3;
    a += __shfl_xor(a, 1);
    a += __shfl_xor(a, 2);
    if (p == 0) {
      int T = k >> 5, q2 = (k >> 3) & 3, jj = k & 7;
      g_wscF[(T*64 + q2*16 + c)*8 + jj] = (__bf16)a;
    }
  } else if (i < C5) {                                  // bs1F zero (c >= 8)
    int j = i - C4;
    int lane = j >> 3, c = lane & 15;
    if (c >= 8) g_bs1F[j] = (__bf16)0.f;
  } else if (i < C6) {                                  // bs1F dots
    int j = i - C5;
    int p = j & 31, c = (j >> 5) & 7, kk = j >> 8;
    int h = c >> 1;
    const float* av = (c & 1) ? (ad1 + h*Hd) : (as1 + h*Hd);
    float acc = 0.f;
    #pragma unroll
    for (int mi = 0; mi < 4; ++mi) {
      int m = p*4 + mi;
      float t0=0.f,t1=0.f,t2=0.f,t3=0.f;
      #pragma unroll
      for (int f = 0; f < Hd; f += 4) {
        t0 += W1[m*W1C + h*Hd + f    ] * av[f    ];
        t1 += W1[m*W1C + h*Hd + f + 1] * av[f + 1];
        t2 += W1[m*W1C + h*Hd + f + 2] * av[f + 2];
        t3 += W1[m*W1C + h*Hd + f + 3] * av[f + 3];
      }
      acc += Wa[kk*Hd + m] * (t0+t1+t2+t3);
    }
    acc += __shfl_xor(acc, 1);
    acc += __shfl_xor(acc, 2);
    acc += __shfl_xor(acc, 4);
    acc += __shfl_xor(acc, 8);
    acc += __shfl_xor(acc, 16);
    if (p == 0) {
      int q2 = kk >> 3, jj = kk & 7;
      g_bs1F[(q2*16 + c)*8 + jj] = (__bf16)acc;
    }
  } else if (i < CP_TOT) {                              // c1s
    int j = i - C6;
    int p = j & 31, c = j >> 5;
    int h = c >> 1;
    const float* av = (c & 1) ? (ad1 + h*Hd) : (as1 + h*Hd);
    float acc = 0.f;
    #pragma unroll
    for (int mi = 0; mi < 4; ++mi) {
      int m = p*4 + mi;
      float t = 0.f;
      #pragma unroll
      for (int f = 0; f < Hd; ++f) t += W1[m*W1C + h*Hd + f] * av[f];
      acc += ba[m] * t;
    }
    acc += __shfl_xor(acc, 1);
    acc += __shfl_xor(acc, 2);
    acc += __shfl_xor(acc, 4);
    acc += __shfl_xor(acc, 8);
    acc += __shfl_xor(acc, 16);
    if (p == 0) g_c1s[c] = acc;
  }
}

// ================= main fused kernel =================
// R11 = R10 structure (hT/eluS alias one 17.4 KB buffer; LDS ~30 KB) with
// __launch_bounds__(256,4): VGPR cap 128 >= natural ~90 demand -> NO SPILL.
// 4 blocks/CU (vs R8's 3) from LDS shrink; R10's (256,5) capped VGPR at 48
// and spilled 234 MB of scratch (the regression).
__global__ __launch_bounds__(BLK, 4) void gat_main(
    const float* __restrict__ emb, const int* __restrict__ ei,
    const float* __restrict__ gate_logits,
    const float* __restrict__ b1, const float* __restrict__ b2,
    const float* __restrict__ Wc1, const float* __restrict__ bc1,
    const float* __restrict__ Wc2, const float* __restrict__ bc2,
    float* __restrict__ out)
{
  __shared__ __align__(16) __bf16 hbuf[Hd * NSTR];  // 17408 B: hT / eluS / cells alias
  __shared__ __align__(16) __bf16 Pbf[Fn * PROW];   //  8704 B: bf16 P [tgt][src]
  __shared__ float sS1s[HEADS][Fn], sS1d[HEADS][Fn];// 2048 B
  __shared__ float sSrc[Fn], sDst[Fn], sSum[Fn], gateS[Fn];
  __shared__ float gpool[Hd], hcS[Fn];
  __shared__ __align__(16) __bf16 wS[Fn];

  __bf16* hT   = hbuf;                              // [feat(128)][node], stride NSTR
  __bf16* eluS = hbuf;                              // [node(64)][feat], stride EROW
  unsigned* cells = (unsigned*)hbuf;                // 4096 u32 (setup only)

  const int b    = blockIdx.x;
  const int tid  = threadIdx.x;
  const int lane = tid & 63;
  const int wv   = tid >> 6;
  const int quad = lane >> 4;
  const int l15  = lane & 15;
  const int nodeBase = wv * 16;
  const int m0   = wv * 32;
  const int base = b * Fn;

  const f32x4 zero4 = {0.f, 0.f, 0.f, 0.f};

  // ---- S1a: zero cells/Pbf/sSum, gate, stage edges to regs ----
  int es = 0, et = 0, ecell = 0;
  if (tid < NE) {
    if (tid < EPG) {
      es = ei[(size_t)b*EPG + tid] - base;
      et = ei[(size_t)Etot + (size_t)b*EPG + tid] - base;
    } else {
      es = et = tid - EPG;
    }
    ecell = et * Fn + es;
  }
  #pragma unroll
  for (int i = 0; i < 16; ++i) cells[tid + i*BLK] = 0u;
  {
    float4* p4 = (float4*)Pbf;                      // 544 float4
    const float4 z4 = {0.f,0.f,0.f,0.f};
    p4[tid] = z4; p4[tid + 256] = z4;
    if (tid < 32) p4[tid + 512] = z4;
  }
  if (tid < Fn) {
    float g = 1.f / (1.f + expf(-gate_logits[tid]));
    gateS[tid] = g; sSum[tid] = 0.f;
    if (b == 0) out[Bg*NC + tid] = g;               // second tuple output (gate)
  }
  // A-fragment of emb (constant across heads)
  bf16x8 Af;
  {
    const float* ar = emb + ((size_t)base + nodeBase + l15) * DIN + quad * 8;
    float4 e0 = *(const float4*)ar;
    float4 e1 = *(const float4*)(ar + 4);
    Af[0]=(__bf16)e0.x; Af[1]=(__bf16)e0.y; Af[2]=(__bf16)e0.z; Af[3]=(__bf16)e0.w;
    Af[4]=(__bf16)e1.x; Af[5]=(__bf16)e1.y; Af[6]=(__bf16)e1.z; Af[7]=(__bf16)e1.w;
  }
  __syncthreads();

  // ---- S1b: edge multiplicity count + layer-1 score MFMA ----
  bool rep = false;
  if (tid < NE) rep = (atomicAdd(&cells[ecell], 1u) == 0u);
  {
    bf16x8 Bs = *(const bf16x8*)(g_bs1F + lane*8);
    f32x4 ds = __builtin_amdgcn_mfma_f32_16x16x32_bf16(Af, Bs, zero4, 0, 0, 0);
    if (l15 < 8) {
      const float cc = g_c1s[l15];
      const int h = l15 >> 1;
      float* dstArr = (l15 & 1) ? &sS1d[h][0] : &sS1s[h][0];
      #pragma unroll
      for (int r = 0; r < 4; ++r) {
        int m = nodeBase + quad*4 + r;
        dstArr[m] = gateS[m] * (ds[r] + cc);
      }
    }
  }
  __syncthreads();

  float fm = 0.f;
  if (tid < NE && rep) fm = (float)cells[ecell];
  __syncthreads();                                  // cells region becomes hT next

  float gq[4];
  #pragma unroll
  for (int r = 0; r < 4; ++r) gq[r] = gateS[nodeBase + quad*4 + r];

  f32x4 acc[8];                                     // GEMM2 accumulators
  #pragma unroll
  for (int i = 0; i < 8; ++i) acc[i] = zero4;
  f32x4 accS = zero4;                               // layer-2 score accumulator

  for (int hh = 0; hh < HEADS; ++hh) {
    // ---- P1: GEMM1 -> hT  ||  edge scatter into Pbf/sSum ----
    #pragma unroll
    for (int Nt = 0; Nt < 8; ++Nt) {
      const int n = Nt*16 + l15;
      bf16x8 Bf = *(const bf16x8*)(g_wcombT + (hh*Hd + n)*DIN + quad*8);  // coalesced
      f32x4 d = __builtin_amdgcn_mfma_f32_16x16x32_bf16(Af, Bf, zero4, 0, 0, 0);
      const float c1v = g_c1[hh*Hd + n];
      bf16x4 hw;
      #pragma unroll
      for (int r = 0; r < 4; ++r) hw[r] = (__bf16)((d[r] + c1v) * gq[r]);
      *(bf16x4*)(hT + n*NSTR + nodeBase + quad*4) = hw;
    }
    if (tid < NE && rep) {
      float e = sS1s[hh][es] + sS1d[hh][et];
      e = (e > 0.f) ? e : 0.2f * e;
      float pe = fm * __expf(e);
      Pbf[et*PROW + es] = (__bf16)pe;
      atomicAdd(&sSum[et], pe);
    }
    __syncthreads();

    // ---- P2 (Cm): aggregation MFMAs + epilogue -> 8 bf16x4 regs (hT dies here) ----
    bf16x4 w[4][2];
    {
      bf16x8 Ac[2][2];
      #pragma unroll
      for (int Mi = 0; Mi < 2; ++Mi)
        #pragma unroll
        for (int Ks = 0; Ks < 2; ++Ks)
          Ac[Mi][Ks] = *(const bf16x8*)(hT + (m0 + Mi*16 + l15)*NSTR + Ks*32 + quad*8);
      float4 b1v[2];
      #pragma unroll
      for (int Mi = 0; Mi < 2; ++Mi)
        b1v[Mi] = *(const float4*)&b1[hh*Hd + m0 + Mi*16 + quad*4];
      #pragma unroll
      for (int Nt = 0; Nt < 4; ++Nt) {
        bf16x8 B0f = *(const bf16x8*)(Pbf + (Nt*16 + l15)*PROW + quad*8);
        bf16x8 B1f = *(const bf16x8*)(Pbf + (Nt*16 + l15)*PROW + 32 + quad*8);
        const int t = Nt*16 + l15;
        const float si = 1.f / (sSum[t] + 1e-16f);
        #pragma unroll
        for (int Mi = 0; Mi < 2; ++Mi) {
          f32x4 d = __builtin_amdgcn_mfma_f32_16x16x32_bf16(Ac[Mi][0], B0f, zero4, 0, 0, 0);
          d = __builtin_amdgcn_mfma_f32_16x16x32_bf16(Ac[Mi][1], B1f, d, 0, 0, 0);
          #pragma unroll
          for (int r = 0; r < 4; ++r) {
            float hv = d[r]*si + b1v[Mi][r];
            hv = (hv > 0.f) ? hv : (__expf(hv) - 1.f);
            w[Nt][Mi][r] = (__bf16)hv;
          }
        }
      }
    }
    __syncthreads();                                // all hT reads + Pbf reads done

    // ---- P3 (Ce): write elu -> eluS (same memory as hT); zero Pbf ----
    #pragma unroll
    for (int Nt = 0; Nt < 4; ++Nt) {
      const int t = Nt*16 + l15;
      #pragma unroll
      for (int Mi = 0; Mi < 2; ++Mi)
        *(bf16x4*)(eluS + t*EROW + m0 + Mi*16 + quad*4) = w[Nt][Mi];
    }
    {
      float4* p4 = (float4*)Pbf;
      const float4 z4 = {0.f,0.f,0.f,0.f};
      p4[tid] = z4; p4[tid + 256] = z4;
      if (tid < 32) p4[tid + 512] = z4;
    }
    __syncthreads();

    // ---- P4 (D): GEMM2 + fused layer-2 score column; zero sSum ----
    #pragma unroll
    for (int Ks = 0; Ks < 4; ++Ks) {
      bf16x8 A2 = *(const bf16x8*)(eluS + (nodeBase + l15)*EROW + Ks*32 + quad*8);
      #pragma unroll
      for (int Nt = 0; Nt < 8; ++Nt) {
        bf16x8 B2 = *(const bf16x8*)(g_w2F + (((hh*4 + Ks)*8 + Nt)*64 + lane)*8);
        acc[Nt] = __builtin_amdgcn_mfma_f32_16x16x32_bf16(A2, B2, acc[Nt], 0, 0, 0);
      }
      bf16x8 Bs2 = *(const bf16x8*)(g_wscF + ((hh*4 + Ks)*64 + lane)*8);
      accS = __builtin_amdgcn_mfma_f32_16x16x32_bf16(A2, Bs2, accS, 0, 0, 0);
    }
    if (tid < Fn) sSum[tid] = 0.f;
    __syncthreads();                                // eluS dies; next P1 rewrites hbuf
  }

  // ---- E: publish h2 -> hT; extract layer-2 scores from accS ----
  #pragma unroll
  for (int Nt = 0; Nt < 8; ++Nt) {
    const int n = Nt*16 + l15;
    bf16x4 hw;
    #pragma unroll
    for (int r = 0; r < 4; ++r) hw[r] = (__bf16)acc[Nt][r];
    *(bf16x4*)(hT + n*NSTR + nodeBase + quad*4) = hw;
  }
  if (l15 == 0) {
    #pragma unroll
    for (int r = 0; r < 4; ++r) sSrc[nodeBase + quad*4 + r] = accS[r];
  } else if (l15 == 1) {
    #pragma unroll
    for (int r = 0; r < 4; ++r) sDst[nodeBase + quad*4 + r] = accS[r];
  }
  __syncthreads();

  // ---- F: layer-2 edge scatter ----
  if (tid < NE && rep) {
    float e = sSrc[es] + sDst[et];
    e = (e > 0.f) ? e : 0.2f * e;
    float pe = fm * __expf(e);
    Pbf[et*PROW + es] = (__bf16)pe;
    atomicAdd(&sSum[et], pe);
  }
  __syncthreads();

  // ---- W: w[s] = (1/64) * sum_t sInv_t * P2[t][s] ----
  {
    const int s_ = tid >> 2, part = tid & 3;
    float a = 0.f;
    #pragma unroll
    for (int q = 0; q < 16; ++q) {
      const int t = part*16 + q;
      a += (1.f / (sSum[t] + 1e-16f)) * (float)Pbf[t*PROW + s_];
    }
    a += __shfl_xor(a, 1);
    a += __shfl_xor(a, 2);
    if (part == 0) wS[s_] = (__bf16)(a * (1.f/64.f));
  }
  __syncthreads();

  // ---- G: gpool[f] = h2^T[f] · w + b2[f] ----
  {
    #pragma unroll
    for (int Mi = 0; Mi < 2; ++Mi) {
      f32x4 d = zero4;
      #pragma unroll
      for (int Ks = 0; Ks < 2; ++Ks) {
        bf16x8 A = *(const bf16x8*)(hT + (m0 + Mi*16 + l15)*NSTR + Ks*32 + quad*8);
        bf16x8 Bw = *(const bf16x8*)(wS + Ks*32 + quad*8);   // broadcast
        d = __builtin_amdgcn_mfma_f32_16x16x32_bf16(A, Bw, d, 0, 0, 0);
      }
      if (l15 == 0) {
        #pragma unroll
        for (int r = 0; r < 4; ++r) {
          const int f = m0 + Mi*16 + quad*4 + r;
          gpool[f] = d[r] + b2[f];
        }
      }
    }
  }
  __syncthreads();

  // ---- classifier layer 1: hc = leaky(g @ Wc1 + bc1), 4 threads/col ----
  {
    const int c = tid >> 2, p = tid & 3;
    float a = 0.f;
    #pragma unroll
    for (int i = 0; i < 32; ++i) {
      const int k = p*32 + i;
      a += gpool[k] * Wc1[k*Fn + c];
    }
    a += __shfl_xor(a, 1);
    a += __shfl_xor(a, 2);
    if (p == 0) {
      a += bc1[c];
      hcS[c] = (a > 0.f) ? a : 0.01f * a;
    }
  }
  __syncthreads();

  // ---- classifier layer 2: logits, 16 threads/col ----
  {
    const int c = tid >> 4, p = tid & 15;
    float a = 0.f;
    #pragma unroll
    for (int i = 0; i < 4; ++i) {
      const int k = p*4 + i;
      a += hcS[k] * Wc2[k*NC + c];
    }
    a += __shfl_xor(a, 1);
    a += __shfl_xor(a, 2);
    a += __shfl_xor(a, 4);
    a += __shfl_xor(a, 8);
    if (p == 0) out[b*NC + c] = a + bc2[c];
  }
}

extern "C" void kernel_launch(void* const* d_in, const int* in_sizes, int n_in,
                              void* d_out, int out_size, void* d_ws, size_t ws_size,
                              hipStream_t stream) {
  const float* emb = (const float*)d_in[0];
  const int*   ei  = (const int*)  d_in[1];
  // d_in[2] = batch_idx (layout known)
  const float* Wa  = (const float*)d_in[3];
  const float* ba  = (const float*)d_in[4];
  const float* gl  = (const float*)d_in[5];
  const float* W1  = (const float*)d_in[6];
  const float* as1 = (const float*)d_in[7];
  const float* ad1 = (const float*)d_in[8];
  const float* b1  = (const float*)d_in[9];
  const float* W2  = (const float*)d_in[10];
  const float* as2 = (const float*)d_in[11];
  const float* ad2 = (const float*)d_in[12];
  const float* b2  = (const float*)d_in[13];
  const float* Wc1 = (const float*)d_in[14];
  const float* bc1 = (const float*)d_in[15];
  const float* Wc2 = (const float*)d_in[16];
  const float* bc2 = (const float*)d_in[17];
  float* out = (float*)d_out;

  hipLaunchKernelGGL(prep, dim3((CP_TOT + BLK - 1)/BLK), dim3(BLK), 0, stream,
                     Wa, ba, W1, W2, as1, ad1, as2, ad2);
  hipLaunchKernelGGL(gat_main, dim3(Bg), dim3(BLK), 0, stream,
                     emb, ei, gl, b1, b2, Wc1, bc1, Wc2, bc2, out);
}

// Round 12
// 208.332 us; speedup vs baseline: 1.4697x; 1.0361x over previous
//
#include <hip/hip_runtime.h>
#include <math.h>

#define BLK 256

constexpr int Bg    = 2048;
constexpr int Fn    = 64;
constexpr int DIN   = 32;
constexpr int Hd    = 128;
constexpr int HEADS = 4;
constexpr int NC    = 16;
constexpr int EPG   = 128;
constexpr int Etot  = Bg * EPG;
constexpr int W1C   = HEADS * Hd;   // 512
constexpr int NSTR  = 68;           // hT row stride (bf16)
constexpr int EROW  = 136;          // eluS row stride (bf16)
constexpr int PROW  = 68;           // Pbf row stride (bf16)
constexpr int NE    = EPG + Fn;     // 192 edges incl self-loops

typedef __attribute__((ext_vector_type(8))) __bf16 bf16x8;
typedef __attribute__((ext_vector_type(4))) __bf16 bf16x4;
typedef __attribute__((ext_vector_type(4))) float  f32x4;

// ---- precomputed weights (single prep kernel) ----
__device__ __align__(16) __bf16 g_wcombT[W1C * DIN];
__device__ float g_c1[W1C];
__device__ float g_c1s[16];
__device__ __align__(16) __bf16 g_w2F[HEADS*4*8*64*8];      // 65536 elems
__device__ __align__(16) __bf16 g_wscF[HEADS*4*64*8];       // 8192 elems
__device__ __align__(16) __bf16 g_bs1F[64*8];               // 512 elems

constexpr int N_WC   = DIN * W1C;
constexpr int C0 = N_WC;
constexpr int C1 = C0 + W1C;
constexpr int C2 = C1 + HEADS*4*8*64*8;
constexpr int C3 = C2 + HEADS*4*64*8;
constexpr int C4 = C3 + 4096;
constexpr int C5 = C4 + 512;
constexpr int C6 = C5 + 8192;
constexpr int CP_TOT = C6 + 256;

__global__ __launch_bounds__(BLK) void prep(
    const float* __restrict__ Wa, const float* __restrict__ ba,
    const float* __restrict__ W1, const float* __restrict__ W2,
    const float* __restrict__ as1, const float* __restrict__ ad1,
    const float* __restrict__ as2, const float* __restrict__ ad2)
{
  __shared__ float WaS[DIN * Hd];
  const int tid = threadIdx.x;
  if (blockIdx.x < 64) {
    for (int i2 = tid; i2 < DIN * Hd; i2 += BLK) {
      int k = i2 >> 7, m = i2 & 127;
      WaS[m * DIN + k] = Wa[i2];
    }
    __syncthreads();
  }

  int i = blockIdx.x * BLK + tid;
  if (i < C0) {                                         // wcombT: i = n*32+k
    int k = i & 31, n = i >> 5;
    float a0=0.f,a1=0.f,a2=0.f,a3=0.f;
    #pragma unroll
    for (int m = 0; m < Hd; m += 4) {
      a0 += WaS[(m  )*DIN + k] * W1[(m  )*W1C + n];
      a1 += WaS[(m+1)*DIN + k] * W1[(m+1)*W1C + n];
      a2 += WaS[(m+2)*DIN + k] * W1[(m+2)*W1C + n];
      a3 += WaS[(m+3)*DIN + k] * W1[(m+3)*W1C + n];
    }
    g_wcombT[i] = (__bf16)(a0+a1+a2+a3);
  } else if (i < C1) {                                  // c1
    int n = i - C0;
    float a0=0.f,a1=0.f,a2=0.f,a3=0.f;
    #pragma unroll
    for (int m = 0; m < Hd; m += 4) {
      a0 += ba[m  ] * W1[(m  )*W1C + n];
      a1 += ba[m+1] * W1[(m+1)*W1C + n];
      a2 += ba[m+2] * W1[(m+2)*W1C + n];
      a3 += ba[m+3] * W1[(m+3)*W1C + n];
    }
    g_c1[n] = a0+a1+a2+a3;
  } else if (i < C2) {                                  // w2F
    int j = i - C1;
    int k = j >> 7, n = j & 127;
    int hh = k >> 7, Ks = (k >> 5) & 3, q = (k >> 3) & 3, jj = k & 7;
    int Nt = n >> 4, l = n & 15;
    int idx = (((hh*4 + Ks)*8 + Nt)*64 + (q*16 + l))*8 + jj;
    g_w2F[idx] = (__bf16)W2[j];
  } else if (i < C3) {                                  // wscF zero (c >= 2)
    int j = i - C2;
    int lane = (j >> 3) & 63, c = lane & 15;
    if (c >= 2) g_wscF[j] = (__bf16)0.f;
  } else if (i < C4) {                                  // wscF dots
    int j = i - C3;
    int p = j & 3, c = (j >> 2) & 1, k = j >> 3;
    const float* av = c ? ad2 : as2;
    float a0=0.f,a1=0.f,a2=0.f,a3=0.f;
    #pragma unroll
    for (int q = 0; q < 32; q += 4) {
      int f = p*32 + q;
      a0 += W2[(size_t)k*Hd + f    ] * av[f    ];
      a1 += W2[(size_t)k*Hd + f + 1] * av[f + 1];
      a2 += W2[(size_t)k*Hd + f + 2] * av[f + 2];
      a3 += W2[(size_t)k*Hd + f + 3] * av[f + 3];
    }
    float a = a0+a1+a2+a3;
    a += __shfl_xor(a, 1);
    a += __shfl_xor(a, 2);
    if (p == 0) {
      int T = k >> 5, q2 = (k >> 3) & 3, jj = k & 7;
      g_wscF[(T*64 + q2*16 + c)*8 + jj] = (__bf16)a;
    }
  } else if (i < C5) {                                  // bs1F zero (c >= 8)
    int j = i - C4;
    int lane = j >> 3, c = lane & 15;
    if (c >= 8) g_bs1F[j] = (__bf16)0.f;
  } else if (i < C6) {                                  // bs1F dots
    int j = i - C5;
    int p = j & 31, c = (j >> 5) & 7, kk = j >> 8;
    int h = c >> 1;
    const float* av = (c & 1) ? (ad1 + h*Hd) : (as1 + h*Hd);
    float acc = 0.f;
    #pragma unroll
    for (int mi = 0; mi < 4; ++mi) {
      int m = p*4 + mi;
      float t0=0.f,t1=0.f,t2=0.f,t3=0.f;
      #pragma unroll
      for (int f = 0; f < Hd; f += 4) {
        t0 += W1[m*W1C + h*Hd + f    ] * av[f    ];
        t1 += W1[m*W1C + h*Hd + f + 1] * av[f + 1];
        t2 += W1[m*W1C + h*Hd + f + 2] * av[f + 2];
        t3 += W1[m*W1C + h*Hd + f + 3] * av[f + 3];
      }
      acc += Wa[kk*Hd + m] * (t0+t1+t2+t3);
    }
    acc += __shfl_xor(acc, 1);
    acc += __shfl_xor(acc, 2);
    acc += __shfl_xor(acc, 4);
    acc += __shfl_xor(acc, 8);
    acc += __shfl_xor(acc, 16);
    if (p == 0) {
      int q2 = kk >> 3, jj = kk & 7;
      g_bs1F[(q2*16 + c)*8 + jj] = (__bf16)acc;
    }
  } else if (i < CP_TOT) {                              // c1s
    int j = i - C6;
    int p = j & 31, c = j >> 5;
    int h = c >> 1;
    const float* av = (c & 1) ? (ad1 + h*Hd) : (as1 + h*Hd);
    float acc = 0.f;
    #pragma unroll
    for (int mi = 0; mi < 4; ++mi) {
      int m = p*4 + mi;
      float t = 0.f;
      #pragma unroll
      for (int f = 0; f < Hd; ++f) t += W1[m*W1C + h*Hd + f] * av[f];
      acc += ba[m] * t;
    }
    acc += __shfl_xor(acc, 1);
    acc += __shfl_xor(acc, 2);
    acc += __shfl_xor(acc, 4);
    acc += __shfl_xor(acc, 8);
    acc += __shfl_xor(acc, 16);
    if (p == 0) g_c1s[c] = acc;
  }
}

// ================= main fused kernel =================
// R12 = R11 structure (hT/eluS alias one 17.4 KB buffer; LDS ~30 KB), but
// NO min-waves hint: __launch_bounds__(256). Lesson from R2/R10/R11: any
// min-waves arg makes LLVM chase a higher occupancy tier and spill
// (R10: 48 VGPR/234 MB scratch; R11: 64 VGPR/32 MB). Natural allocation is
// ~96-120 VGPR with ZERO spill (R1/R8); LDS caps us at 5 blocks/CU anyway.
__global__ __launch_bounds__(BLK) void gat_main(
    const float* __restrict__ emb, const int* __restrict__ ei,
    const float* __restrict__ gate_logits,
    const float* __restrict__ b1, const float* __restrict__ b2,
    const float* __restrict__ Wc1, const float* __restrict__ bc1,
    const float* __restrict__ Wc2, const float* __restrict__ bc2,
    float* __restrict__ out)
{
  __shared__ __align__(16) __bf16 hbuf[Hd * NSTR];  // 17408 B: hT / eluS / cells alias
  __shared__ __align__(16) __bf16 Pbf[Fn * PROW];   //  8704 B: bf16 P [tgt][src]
  __shared__ float sS1s[HEADS][Fn], sS1d[HEADS][Fn];// 2048 B
  __shared__ float sSrc[Fn], sDst[Fn], sSum[Fn], gateS[Fn];
  __shared__ float gpool[Hd], hcS[Fn];
  __shared__ __align__(16) __bf16 wS[Fn];

  __bf16* hT   = hbuf;                              // [feat(128)][node], stride NSTR
  __bf16* eluS = hbuf;                              // [node(64)][feat], stride EROW
  unsigned* cells = (unsigned*)hbuf;                // 4096 u32 (setup only)

  const int b    = blockIdx.x;
  const int tid  = threadIdx.x;
  const int lane = tid & 63;
  const int wv   = tid >> 6;
  const int quad = lane >> 4;
  const int l15  = lane & 15;
  const int nodeBase = wv * 16;
  const int m0   = wv * 32;
  const int base = b * Fn;

  const f32x4 zero4 = {0.f, 0.f, 0.f, 0.f};

  // ---- S1a: zero cells/Pbf/sSum, gate, stage edges to regs ----
  int es = 0, et = 0, ecell = 0;
  if (tid < NE) {
    if (tid < EPG) {
      es = ei[(size_t)b*EPG + tid] - base;
      et = ei[(size_t)Etot + (size_t)b*EPG + tid] - base;
    } else {
      es = et = tid - EPG;
    }
    ecell = et * Fn + es;
  }
  #pragma unroll
  for (int i = 0; i < 16; ++i) cells[tid + i*BLK] = 0u;
  {
    float4* p4 = (float4*)Pbf;                      // 544 float4
    const float4 z4 = {0.f,0.f,0.f,0.f};
    p4[tid] = z4; p4[tid + 256] = z4;
    if (tid < 32) p4[tid + 512] = z4;
  }
  if (tid < Fn) {
    float g = 1.f / (1.f + expf(-gate_logits[tid]));
    gateS[tid] = g; sSum[tid] = 0.f;
    if (b == 0) out[Bg*NC + tid] = g;               // second tuple output (gate)
  }
  // A-fragment of emb (constant across heads)
  bf16x8 Af;
  {
    const float* ar = emb + ((size_t)base + nodeBase + l15) * DIN + quad * 8;
    float4 e0 = *(const float4*)ar;
    float4 e1 = *(const float4*)(ar + 4);
    Af[0]=(__bf16)e0.x; Af[1]=(__bf16)e0.y; Af[2]=(__bf16)e0.z; Af[3]=(__bf16)e0.w;
    Af[4]=(__bf16)e1.x; Af[5]=(__bf16)e1.y; Af[6]=(__bf16)e1.z; Af[7]=(__bf16)e1.w;
  }
  __syncthreads();

  // ---- S1b: edge multiplicity count + layer-1 score MFMA ----
  bool rep = false;
  if (tid < NE) rep = (atomicAdd(&cells[ecell], 1u) == 0u);
  {
    bf16x8 Bs = *(const bf16x8*)(g_bs1F + lane*8);
    f32x4 ds = __builtin_amdgcn_mfma_f32_16x16x32_bf16(Af, Bs, zero4, 0, 0, 0);
    if (l15 < 8) {
      const float cc = g_c1s[l15];
      const int h = l15 >> 1;
      float* dstArr = (l15 & 1) ? &sS1d[h][0] : &sS1s[h][0];
      #pragma unroll
      for (int r = 0; r < 4; ++r) {
        int m = nodeBase + quad*4 + r;
        dstArr[m] = gateS[m] * (ds[r] + cc);
      }
    }
  }
  __syncthreads();

  float fm = 0.f;
  if (tid < NE && rep) fm = (float)cells[ecell];
  __syncthreads();                                  // cells region becomes hT next

  float gq[4];
  #pragma unroll
  for (int r = 0; r < 4; ++r) gq[r] = gateS[nodeBase + quad*4 + r];

  f32x4 acc[8];                                     // GEMM2 accumulators
  #pragma unroll
  for (int i = 0; i < 8; ++i) acc[i] = zero4;
  f32x4 accS = zero4;                               // layer-2 score accumulator

  for (int hh = 0; hh < HEADS; ++hh) {
    // ---- P1: GEMM1 -> hT  ||  edge scatter into Pbf/sSum ----
    #pragma unroll
    for (int Nt = 0; Nt < 8; ++Nt) {
      const int n = Nt*16 + l15;
      bf16x8 Bf = *(const bf16x8*)(g_wcombT + (hh*Hd + n)*DIN + quad*8);  // coalesced
      f32x4 d = __builtin_amdgcn_mfma_f32_16x16x32_bf16(Af, Bf, zero4, 0, 0, 0);
      const float c1v = g_c1[hh*Hd + n];
      bf16x4 hw;
      #pragma unroll
      for (int r = 0; r < 4; ++r) hw[r] = (__bf16)((d[r] + c1v) * gq[r]);
      *(bf16x4*)(hT + n*NSTR + nodeBase + quad*4) = hw;
    }
    if (tid < NE && rep) {
      float e = sS1s[hh][es] + sS1d[hh][et];
      e = (e > 0.f) ? e : 0.2f * e;
      float pe = fm * __expf(e);
      Pbf[et*PROW + es] = (__bf16)pe;
      atomicAdd(&sSum[et], pe);
    }
    __syncthreads();

    // ---- P2 (Cm): aggregation MFMAs + epilogue -> 8 bf16x4 regs (hT dies here) ----
    bf16x4 w[4][2];
    {
      bf16x8 Ac[2][2];
      #pragma unroll
      for (int Mi = 0; Mi < 2; ++Mi)
        #pragma unroll
        for (int Ks = 0; Ks < 2; ++Ks)
          Ac[Mi][Ks] = *(const bf16x8*)(hT + (m0 + Mi*16 + l15)*NSTR + Ks*32 + quad*8);
      float4 b1v[2];
      #pragma unroll
      for (int Mi = 0; Mi < 2; ++Mi)
        b1v[Mi] = *(const float4*)&b1[hh*Hd + m0 + Mi*16 + quad*4];
      #pragma unroll
      for (int Nt = 0; Nt < 4; ++Nt) {
        bf16x8 B0f = *(const bf16x8*)(Pbf + (Nt*16 + l15)*PROW + quad*8);
        bf16x8 B1f = *(const bf16x8*)(Pbf + (Nt*16 + l15)*PROW + 32 + quad*8);
        const int t = Nt*16 + l15;
        const float si = 1.f / (sSum[t] + 1e-16f);
        #pragma unroll
        for (int Mi = 0; Mi < 2; ++Mi) {
          f32x4 d = __builtin_amdgcn_mfma_f32_16x16x32_bf16(Ac[Mi][0], B0f, zero4, 0, 0, 0);
          d = __builtin_amdgcn_mfma_f32_16x16x32_bf16(Ac[Mi][1], B1f, d, 0, 0, 0);
          #pragma unroll
          for (int r = 0; r < 4; ++r) {
            float hv = d[r]*si + b1v[Mi][r];
            hv = (hv > 0.f) ? hv : (__expf(hv) - 1.f);
            w[Nt][Mi][r] = (__bf16)hv;
          }
        }
      }
    }
    __syncthreads();                                // all hT reads + Pbf reads done

    // ---- P3 (Ce): write elu -> eluS (same memory as hT); zero Pbf ----
    #pragma unroll
    for (int Nt = 0; Nt < 4; ++Nt) {
      const int t = Nt*16 + l15;
      #pragma unroll
      for (int Mi = 0; Mi < 2; ++Mi)
        *(bf16x4*)(eluS + t*EROW + m0 + Mi*16 + quad*4) = w[Nt][Mi];
    }
    {
      float4* p4 = (float4*)Pbf;
      const float4 z4 = {0.f,0.f,0.f,0.f};
      p4[tid] = z4; p4[tid + 256] = z4;
      if (tid < 32) p4[tid + 512] = z4;
    }
    __syncthreads();

    // ---- P4 (D): GEMM2 + fused layer-2 score column; zero sSum ----
    #pragma unroll
    for (int Ks = 0; Ks < 4; ++Ks) {
      bf16x8 A2 = *(const bf16x8*)(eluS + (nodeBase + l15)*EROW + Ks*32 + quad*8);
      #pragma unroll
      for (int Nt = 0; Nt < 8; ++Nt) {
        bf16x8 B2 = *(const bf16x8*)(g_w2F + (((hh*4 + Ks)*8 + Nt)*64 + lane)*8);
        acc[Nt] = __builtin_amdgcn_mfma_f32_16x16x32_bf16(A2, B2, acc[Nt], 0, 0, 0);
      }
      bf16x8 Bs2 = *(const bf16x8*)(g_wscF + ((hh*4 + Ks)*64 + lane)*8);
      accS = __builtin_amdgcn_mfma_f32_16x16x32_bf16(A2, Bs2, accS, 0, 0, 0);
    }
    if (tid < Fn) sSum[tid] = 0.f;
    __syncthreads();                                // eluS dies; next P1 rewrites hbuf
  }

  // ---- E: publish h2 -> hT; extract layer-2 scores from accS ----
  #pragma unroll
  for (int Nt = 0; Nt < 8; ++Nt) {
    const int n = Nt*16 + l15;
    bf16x4 hw;
    #pragma unroll
    for (int r = 0; r < 4; ++r) hw[r] = (__bf16)acc[Nt][r];
    *(bf16x4*)(hT + n*NSTR + nodeBase + quad*4) = hw;
  }
  if (l15 == 0) {
    #pragma unroll
    for (int r = 0; r < 4; ++r) sSrc[nodeBase + quad*4 + r] = accS[r];
  } else if (l15 == 1) {
    #pragma unroll
    for (int r = 0; r < 4; ++r) sDst[nodeBase + quad*4 + r] = accS[r];
  }
  __syncthreads();

  // ---- F: layer-2 edge scatter ----
  if (tid < NE && rep) {
    float e = sSrc[es] + sDst[et];
    e = (e > 0.f) ? e : 0.2f * e;
    float pe = fm * __expf(e);
    Pbf[et*PROW + es] = (__bf16)pe;
    atomicAdd(&sSum[et], pe);
  }
  __syncthreads();

  // ---- W: w[s] = (1/64) * sum_t sInv_t * P2[t][s] ----
  {
    const int s_ = tid >> 2, part = tid & 3;
    float a = 0.f;
    #pragma unroll
    for (int q = 0; q < 16; ++q) {
      const int t = part*16 + q;
      a += (1.f / (sSum[t] + 1e-16f)) * (float)Pbf[t*PROW + s_];
    }
    a += __shfl_xor(a, 1);
    a += __shfl_xor(a, 2);
    if (part == 0) wS[s_] = (__bf16)(a * (1.f/64.f));
  }
  __syncthreads();

  // ---- G: gpool[f] = h2^T[f] · w + b2[f] ----
  {
    #pragma unroll
    for (int Mi = 0; Mi < 2; ++Mi) {
      f32x4 d = zero4;
      #pragma unroll
      for (int Ks = 0; Ks < 2; ++Ks) {
        bf16x8 A = *(const bf16x8*)(hT + (m0 + Mi*16 + l15)*NSTR + Ks*32 + quad*8);
        bf16x8 Bw = *(const bf16x8*)(wS + Ks*32 + quad*8);   // broadcast
        d = __builtin_amdgcn_mfma_f32_16x16x32_bf16(A, Bw, d, 0, 0, 0);
      }
      if (l15 == 0) {
        #pragma unroll
        for (int r = 0; r < 4; ++r) {
          const int f = m0 + Mi*16 + quad*4 + r;
          gpool[f] = d[r] + b2[f];
        }
      }
    }
  }
  __syncthreads();

  // ---- classifier layer 1: hc = leaky(g @ Wc1 + bc1), 4 threads/col ----
  {
    const int c = tid >> 2, p = tid & 3;
    float a = 0.f;
    #pragma unroll
    for (int i = 0; i < 32; ++i) {
      const int k = p*32 + i;
      a += gpool[k] * Wc1[k*Fn + c];
    }
    a += __shfl_xor(a, 1);
    a += __shfl_xor(a, 2);
    if (p == 0) {
      a += bc1[c];
      hcS[c] = (a > 0.f) ? a : 0.01f * a;
    }
  }
  __syncthreads();

  // ---- classifier layer 2: logits, 16 threads/col ----
  {
    const int c = tid >> 4, p = tid & 15;
    float a = 0.f;
    #pragma unroll
    for (int i = 0; i < 4; ++i) {
      const int k = p*4 + i;
      a += hcS[k] * Wc2[k*NC + c];
    }
    a += __shfl_xor(a, 1);
    a += __shfl_xor(a, 2);
    a += __shfl_xor(a, 4);
    a += __shfl_xor(a, 8);
    if (p == 0) out[b*NC + c] = a + bc2[c];
  }
}

extern "C" void kernel_launch(void* const* d_in, const int* in_sizes, int n_in,
                              void* d_out, int out_size, void* d_ws, size_t ws_size,
                              hipStream_t stream) {
  const float* emb = (const float*)d_in[0];
  const int*   ei  = (const int*)  d_in[1];
  // d_in[2] = batch_idx (layout known)
  const float* Wa  = (const float*)d_in[3];
  const float* ba  = (const float*)d_in[4];
  const float* gl  = (const float*)d_in[5];
  const float* W1  = (const float*)d_in[6];
  const float* as1 = (const float*)d_in[7];
  const float* ad1 = (const float*)d_in[8];
  const float* b1  = (const float*)d_in[9];
  const float* W2  = (const float*)d_in[10];
  const float* as2 = (const float*)d_in[11];
  const float* ad2 = (const float*)d_in[12];
  const float* b2  = (const float*)d_in[13];
  const float* Wc1 = (const float*)d_in[14];
  const float* bc1 = (const float*)d_in[15];
  const float* Wc2 = (const float*)d_in[16];
  const float* bc2 = (const float*)d_in[17];
  float* out = (float*)d_out;

  hipLaunchKernelGGL(prep, dim3((CP_TOT + BLK - 1)/BLK), dim3(BLK), 0, stream,
                     Wa, ba, W1, W2, as1, ad1, as2, ad2);
  hipLaunchKernelGGL(gat_main, dim3(Bg), dim3(BLK), 0, stream,
                     emb, ei, gl, b1, b2, Wc1, bc1, Wc2, bc2, out);
}